// Round 1
// baseline (78084.552 us; speedup 1.0000x reference)
//
#include <hip/hip_runtime.h>
#include <math.h>

// AutoregTransformer: D=512, HID=2048, NH=8(hd=64), L=4, T=32, B=16. All fp32.
// Persistent cooperative-style kernel: 256 blocks x 256 threads, manual grid
// barrier (monotonic counter, agent-scope atomics). ws usage ~7.6 MB.
//
// Key algebraic simplifications vs reference:
//  - encoder self-attn (S=1): softmax==1 -> attn out == V; Q/K projections dead.
//  - decoder cross-attn (mem S=1): output == out_proj(V(mem)) constant per
//    (layer, batch); precomputed once before the decode loop.

#define NB 256
#define NT 256
#define Dm 512
#define HIDN 2048
#define TLEN 32
#define BSZ 16
#define NLAY 4

struct Params {
  const float* y; const float* start;
  const float *eqw, *eqb, *eow, *eob, *ef1w, *ef1b, *ef2w, *ef2b;
  const float *eln1g, *eln1b, *eln2g, *eln2b, *elnfg, *elnfb;
  const float *dqw, *dqb, *dow, *dob, *dxqw, *dxqb, *dxow, *dxob;
  const float *df1w, *df1b, *df2w, *df2b;
  const float *dln1g, *dln1b, *dln2g, *dln2b, *dln3g, *dln3b, *dlnfg, *dlnfb;
  float* out; float* ws;
};

struct ABp { float hs[32][128]; float q[32][64]; float k[32][64]; float v[32][64]; float sc[32][32]; };

union Smem {
  ABp ab;                                   // 45056 B
  struct { float xs[16][Dm]; } d;           // 32768 B
  struct { float xs[8][Dm]; float outb[8][Dm]; } ce; // 32768 B
};

__device__ __forceinline__ float dot4f(float4 a, float4 b) {
  return a.x*b.x + a.y*b.y + a.z*b.z + a.w*b.w;
}

// LayerNorm over one 512-row held as 8 vals/lane across a 64-lane wave.
__device__ __forceinline__ void wave_ln(float v[8], const float* __restrict__ g,
                                        const float* __restrict__ bt, int cb) {
  float sum = 0.f, sq = 0.f;
#pragma unroll
  for (int q = 0; q < 8; ++q) { sum += v[q]; sq += v[q]*v[q]; }
#pragma unroll
  for (int m = 32; m; m >>= 1) { sum += __shfl_xor(sum, m, 64); sq += __shfl_xor(sq, m, 64); }
  float mean = sum * (1.f/Dm);
  float var  = sq  * (1.f/Dm) - mean*mean;
  float rs = rsqrtf(var + 1e-5f);
#pragma unroll
  for (int q = 0; q < 8; ++q) v[q] = (v[q]-mean)*rs*g[cb+q] + bt[cb+q];
}

// h0 = tgt[b,j,:] + pe[j,:]  (tgt row 0 = start_vec; rows >=1 live in d_out)
__device__ __forceinline__ float h0v(const Params& p, const float* __restrict__ pe,
                                     int b, int j, int c) {
  float tg = (j == 0) ? p.start[c] : p.out[(size_t)(b*TLEN + (j-1))*Dm + c];
  return tg + pe[j*Dm + c];
}

// GEMM tile: out[8][512] = A[8][K] @ W[512][K]^T + bias.  A rows global
// (stride K), W row-major [512][K].  Thread t owns cols t and t+256.
template<int K>
__device__ void gemm_tile(const float* __restrict__ A0, const float* __restrict__ W,
                          const float* __restrict__ bias,
                          float (* __restrict__ xs)[Dm], float (* __restrict__ outL)[Dm]) {
  const int t = threadIdx.x;
  float acc0[8], acc1[8];
#pragma unroll
  for (int r = 0; r < 8; ++r) { acc0[r] = 0.f; acc1[r] = 0.f; }
  for (int kc = 0; kc < K/Dm; ++kc) {
    for (int i = t; i < 8*Dm; i += NT) {
      int r = i >> 9, k = i & (Dm-1);
      xs[r][k] = A0[(size_t)r*K + kc*Dm + k];
    }
    __syncthreads();
    const float4* W4a = (const float4*)(W + (size_t)t*K + kc*Dm);
    const float4* W4b = (const float4*)(W + (size_t)(t+NT)*K + kc*Dm);
    for (int k4 = 0; k4 < Dm/4; ++k4) {
      float4 wa = W4a[k4], wb = W4b[k4];
#pragma unroll
      for (int r = 0; r < 8; ++r) {
        float4 x = ((const float4*)xs[r])[k4];
        acc0[r] += dot4f(x, wa);
        acc1[r] += dot4f(x, wb);
      }
    }
    __syncthreads();
  }
#pragma unroll
  for (int r = 0; r < 8; ++r) {
    outL[r][t]    = acc0[r] + bias[t];
    outL[r][t+NT] = acc1[r] + bias[t+NT];
  }
  __syncthreads();
}

__device__ __forceinline__ void raw_store(float* __restrict__ dst, float (* __restrict__ outL)[Dm]) {
  for (int i = threadIdx.x; i < 8*Dm; i += NT)
    dst[(size_t)(i >> 9)*Dm + (i & (Dm-1))] = outL[i >> 9][i & (Dm-1)];
  __syncthreads();
}

// FFN1 tile: U[r0..r0+15][c0..c0+255] = gelu(X[16 rows][512] @ W1^T + b1)
__device__ void ffn1_tile(const float* __restrict__ X, int r0, int c0,
                          const float* __restrict__ W1, const float* __restrict__ b1,
                          float* __restrict__ U, float (* __restrict__ xs)[Dm]) {
  const int t = threadIdx.x;
  for (int i = t; i < 16*Dm; i += NT) {
    int r = i >> 9, k = i & (Dm-1);
    xs[r][k] = X[(size_t)(r0+r)*Dm + k];
  }
  __syncthreads();
  int c = c0 + t;
  const float4* w4 = (const float4*)(W1 + (size_t)c*Dm);
  float acc[16];
#pragma unroll
  for (int r = 0; r < 16; ++r) acc[r] = 0.f;
  for (int k4 = 0; k4 < Dm/4; ++k4) {
    float4 w = w4[k4];
#pragma unroll
    for (int r = 0; r < 16; ++r) acc[r] += dot4f(((const float4*)xs[r])[k4], w);
  }
  float bb = b1[c];
#pragma unroll
  for (int r = 0; r < 16; ++r) {
    float u = acc[r] + bb;
    u = 0.5f*u*(1.0f + erff(u*0.70710678118654752f));
    U[(size_t)(r0+r)*HIDN + c] = u;
  }
  __syncthreads();
}

// Fused per-(batch,head) self-attention: QKV proj + scores + softmax + P@V.
__device__ void ab_phase(const Params& p, const float* __restrict__ pe,
                         const float* __restrict__ hbuf, float* __restrict__ ob,
                         int l, int s, int bid, ABp& ab) {
  const int t = threadIdx.x;
  int b = bid >> 3, h = bid & 7;
  const int nitems = s * 192;
  float acc[24];
#pragma unroll
  for (int m = 0; m < 24; ++m) acc[m] = 0.f;
  for (int kc = 0; kc < 4; ++kc) {
    for (int i = t; i < s*128; i += NT) {
      int j = i >> 7, k = i & 127;
      int c = kc*128 + k;
      ab.hs[j][k] = (l == 0) ? h0v(p, pe, b, j, c)
                             : hbuf[(size_t)(b*s + j)*Dm + c];
    }
    __syncthreads();
#pragma unroll
    for (int m = 0; m < 24; ++m) {
      int idx = t + m*NT;
      if (idx < nitems) {
        int j = idx / 192, oc = idx % 192;
        int type = oc >> 6, dd = oc & 63;
        const float4* w4 = (const float4*)(p.dqw + ((size_t)l*3*Dm + type*Dm + h*64 + dd)*Dm + kc*128);
        const float4* x4 = (const float4*)ab.hs[j];
        float a = 0.f;
        for (int k4 = 0; k4 < 32; ++k4) a += dot4f(x4[k4], w4[k4]);
        acc[m] += a;
      }
    }
    __syncthreads();
  }
#pragma unroll
  for (int m = 0; m < 24; ++m) {
    int idx = t + m*NT;
    if (idx < nitems) {
      int j = idx / 192, oc = idx % 192;
      int type = oc >> 6, dd = oc & 63;
      float val = acc[m] + p.dqb[l*3*Dm + type*Dm + h*64 + dd];
      if (type == 0)      ab.q[j][dd] = val * 0.125f;   // 1/sqrt(64)
      else if (type == 1) ab.k[j][dd] = val;
      else                ab.v[j][dd] = val;
    }
  }
  __syncthreads();
  // scores [s][s]
  for (int idx = t; idx < s*s; idx += NT) {
    int j = idx / s, j2 = idx - j*s;
    const float4* q4 = (const float4*)ab.q[j];
    const float4* k4 = (const float4*)ab.k[j2];
    float a = 0.f;
#pragma unroll
    for (int x = 0; x < 16; ++x) a += dot4f(q4[x], k4[x]);
    ab.sc[j][j2] = a;
  }
  __syncthreads();
  // softmax rows (wave per row)
  int wave = t >> 6, lane = t & 63;
  for (int j = wave; j < s; j += 4) {
    float sv = (lane < s) ? ab.sc[j][lane] : -3.0e38f;
    float mx = sv;
#pragma unroll
    for (int m = 32; m; m >>= 1) mx = fmaxf(mx, __shfl_xor(mx, m, 64));
    float e = (lane < s) ? expf(sv - mx) : 0.f;
    float sum = e;
#pragma unroll
    for (int m = 32; m; m >>= 1) sum += __shfl_xor(sum, m, 64);
    if (lane < s) ab.sc[j][lane] = e / sum;
  }
  __syncthreads();
  // O = P @ V -> ob[b*s+j][h*64+dd]
  for (int idx = t; idx < s*64; idx += NT) {
    int j = idx >> 6, dd = idx & 63;
    float a = 0.f;
    for (int j2 = 0; j2 < s; ++j2) a += ab.sc[j][j2] * ab.v[j2][dd];
    ob[(size_t)(b*s + j)*Dm + h*64 + dd] = a;
  }
}

#define GBAR() do {                                                              \
    __syncthreads(); ++epoch;                                                    \
    if (t == 0) {                                                                \
      __hip_atomic_fetch_add(cnt, 1u, __ATOMIC_RELEASE, __HIP_MEMORY_SCOPE_AGENT);\
      unsigned tgt_ = epoch * (unsigned)NB;                                      \
      while (__hip_atomic_load(cnt, __ATOMIC_RELAXED, __HIP_MEMORY_SCOPE_AGENT) < tgt_) \
        __builtin_amdgcn_s_sleep(2);                                             \
      __hip_atomic_load(cnt, __ATOMIC_ACQUIRE, __HIP_MEMORY_SCOPE_AGENT);        \
    }                                                                            \
    __syncthreads();                                                             \
  } while (0)

__global__ __launch_bounds__(NT) void ar_transformer(Params p) {
  __shared__ Smem sm;
  const int bid = blockIdx.x;
  const int t = threadIdx.x;
  unsigned epoch = 0;
  unsigned* cnt = (unsigned*)p.ws;
  float* pe    = p.ws + 64;
  float* memb  = pe + TLEN*Dm;
  float* cross = memb + BSZ*Dm;
  float* hbuf  = cross + NLAY*BSZ*Dm;
  float* h2b   = hbuf + 512*Dm;
  float* ob    = h2b + 512*Dm;
  float* ub    = ob + 512*Dm;          // 512*2048 floats
  const int wave = t >> 6, lane = t & 63, cb = (t & 63) * 8;

  // ---- P0: positional encoding + encoder input x = y + pe[0] ----
  for (int i = bid*NT + t; i < TLEN*Dm; i += NB*NT) {
    int tt = i >> 9, d = i & (Dm-1);
    int half = d >> 1;
    float ang = (float)tt * expf(-(float)(2*half) * (9.210340371976184f/512.0f));
    pe[i] = (d & 1) ? cosf(ang) : sinf(ang);
  }
  for (int i = bid*NT + t; i < BSZ*Dm; i += NB*NT) {
    int d = i & (Dm-1);
    hbuf[i] = p.y[i] + ((d & 1) ? 1.0f : 0.0f);   // pe[0]: sin(0)=0, cos(0)=1
  }
  GBAR();

  // ---- Encoder (S=1: attn out == V) ----
  for (int l = 0; l < NLAY; ++l) {
    // V projection -> ob
    for (int it = bid; it < 2; it += NB) {
      gemm_tile<Dm>(hbuf + (size_t)it*8*Dm,
                    p.eqw + ((size_t)l*3*Dm + 2*Dm)*Dm, p.eqb + l*3*Dm + 2*Dm,
                    sm.ce.xs, sm.ce.outb);
      raw_store(ob + (size_t)it*8*Dm, sm.ce.outb);
    }
    GBAR();
    // out proj + LN1 -> h2b
    for (int it = bid; it < 2; it += NB) {
      gemm_tile<Dm>(ob + (size_t)it*8*Dm, p.eow + (size_t)l*Dm*Dm, p.eob + l*Dm,
                    sm.ce.xs, sm.ce.outb);
      for (int rr = wave; rr < 8; rr += 4) {
        int r = it*8 + rr;
        float v[8];
#pragma unroll
        for (int q = 0; q < 8; ++q) v[q] = hbuf[(size_t)r*Dm + cb+q] + sm.ce.outb[rr][cb+q];
        wave_ln(v, p.eln1g + l*Dm, p.eln1b + l*Dm, cb);
#pragma unroll
        for (int q = 0; q < 8; ++q) h2b[(size_t)r*Dm + cb+q] = v[q];
      }
      __syncthreads();
    }
    GBAR();
    // FFN1 -> ub
    for (int it = bid; it < 8; it += NB)
      ffn1_tile(h2b, 0, it*256, p.ef1w + (size_t)l*HIDN*Dm, p.ef1b + l*HIDN, ub, sm.d.xs);
    GBAR();
    // FFN2 + LN2 -> hbuf
    for (int it = bid; it < 2; it += NB) {
      gemm_tile<HIDN>(ub + (size_t)it*8*HIDN, p.ef2w + (size_t)l*Dm*HIDN, p.ef2b + l*Dm,
                      sm.ce.xs, sm.ce.outb);
      for (int rr = wave; rr < 8; rr += 4) {
        int r = it*8 + rr;
        float v[8];
#pragma unroll
        for (int q = 0; q < 8; ++q) v[q] = h2b[(size_t)r*Dm + cb+q] + sm.ce.outb[rr][cb+q];
        wave_ln(v, p.eln2g + l*Dm, p.eln2b + l*Dm, cb);
#pragma unroll
        for (int q = 0; q < 8; ++q) hbuf[(size_t)r*Dm + cb+q] = v[q];
      }
      __syncthreads();
    }
    GBAR();
  }
  // final encoder LN -> memb
  if (bid == 0) {
    for (int r = wave; r < BSZ; r += 4) {
      float v[8];
#pragma unroll
      for (int q = 0; q < 8; ++q) v[q] = hbuf[(size_t)r*Dm + cb+q];
      wave_ln(v, p.elnfg, p.elnfb, cb);
#pragma unroll
      for (int q = 0; q < 8; ++q) memb[(size_t)r*Dm + cb+q] = v[q];
    }
  }
  GBAR();
  // cross-attn precompute: cross[l][b][:] = (mem @ Wxv^T + bxv) @ Wxo^T + bxo
  for (int it = bid; it < 2*NLAY; it += NB) {
    int l = it >> 1, half = it & 1;
    gemm_tile<Dm>(memb + (size_t)half*8*Dm,
                  p.dxqw + ((size_t)l*3*Dm + 2*Dm)*Dm, p.dxqb + l*3*Dm + 2*Dm,
                  sm.ce.xs, sm.ce.outb);
    raw_store(ub + (size_t)(l*BSZ + half*8)*Dm, sm.ce.outb);
  }
  GBAR();
  for (int it = bid; it < 2*NLAY; it += NB) {
    int l = it >> 1, half = it & 1;
    gemm_tile<Dm>(ub + (size_t)(l*BSZ + half*8)*Dm,
                  p.dxow + (size_t)l*Dm*Dm, p.dxob + l*Dm,
                  sm.ce.xs, sm.ce.outb);
    raw_store(cross + (size_t)(l*BSZ + half*8)*Dm, sm.ce.outb);
  }
  GBAR();

  // ---- Autoregressive decode ----
  for (int st = 0; st < TLEN; ++st) {
    const int s = st + 1;
    for (int l = 0; l < NLAY; ++l) {
      // AB: fused self-attention per (b, head)
      if (bid < BSZ*8) ab_phase(p, pe, hbuf, ob, l, s, bid, sm.ab);
      GBAR();
      // C: out proj + LN1 + cross + LN2 -> h2b
      for (int it = bid; it < 2*s; it += NB) {
        gemm_tile<Dm>(ob + (size_t)it*8*Dm, p.dow + (size_t)l*Dm*Dm, p.dob + l*Dm,
                      sm.ce.xs, sm.ce.outb);
        for (int rr = wave; rr < 8; rr += 4) {
          int gr = it*8 + rr;
          int b = gr / s, j = gr - b*s;
          float v[8];
#pragma unroll
          for (int q = 0; q < 8; ++q) {
            int c = cb + q;
            float h0 = (l == 0) ? h0v(p, pe, b, j, c) : hbuf[(size_t)gr*Dm + c];
            v[q] = h0 + sm.ce.outb[rr][c];
          }
          wave_ln(v, p.dln1g + l*Dm, p.dln1b + l*Dm, cb);
#pragma unroll
          for (int q = 0; q < 8; ++q) v[q] += cross[(size_t)(l*BSZ + b)*Dm + cb+q];
          wave_ln(v, p.dln2g + l*Dm, p.dln2b + l*Dm, cb);
#pragma unroll
          for (int q = 0; q < 8; ++q) h2b[(size_t)gr*Dm + cb+q] = v[q];
        }
        __syncthreads();
      }
      GBAR();
      // D: FFN1 -> ub
      for (int it = bid; it < 8*s; it += NB) {
        int rt = it % s, ct = it / s;
        ffn1_tile(h2b, rt*16, ct*256, p.df1w + (size_t)l*HIDN*Dm, p.df1b + l*HIDN, ub, sm.d.xs);
      }
      GBAR();
      // E: FFN2 + LN3 -> hbuf (+ final LN & token append on last layer)
      for (int it = bid; it < 2*s; it += NB) {
        gemm_tile<HIDN>(ub + (size_t)it*8*HIDN, p.df2w + (size_t)l*Dm*HIDN, p.df2b + l*Dm,
                        sm.ce.xs, sm.ce.outb);
        for (int rr = wave; rr < 8; rr += 4) {
          int gr = it*8 + rr;
          int b = gr / s, j = gr - b*s;
          float v[8];
#pragma unroll
          for (int q = 0; q < 8; ++q) v[q] = h2b[(size_t)gr*Dm + cb+q] + sm.ce.outb[rr][cb+q];
          wave_ln(v, p.dln3g + l*Dm, p.dln3b + l*Dm, cb);
#pragma unroll
          for (int q = 0; q < 8; ++q) hbuf[(size_t)gr*Dm + cb+q] = v[q];
          if (l == NLAY-1 && j == s-1) {
            wave_ln(v, p.dlnfg, p.dlnfb, cb);
#pragma unroll
            for (int q = 0; q < 8; ++q) p.out[(size_t)(b*TLEN + st)*Dm + cb+q] = v[q];
          }
        }
        __syncthreads();
      }
      GBAR();
    }
  }
}

extern "C" void kernel_launch(void* const* d_in, const int* in_sizes, int n_in,
                              void* d_out, int out_size, void* d_ws, size_t ws_size,
                              hipStream_t stream) {
  Params P;
  P.y     = (const float*)d_in[0];
  P.start = (const float*)d_in[1];
  // d_in[2] = target_length (int scalar) -- fixed to 32, unused
  P.eqw  = (const float*)d_in[3];  P.eqb  = (const float*)d_in[4];
  P.eow  = (const float*)d_in[5];  P.eob  = (const float*)d_in[6];
  P.ef1w = (const float*)d_in[7];  P.ef1b = (const float*)d_in[8];
  P.ef2w = (const float*)d_in[9];  P.ef2b = (const float*)d_in[10];
  P.eln1g = (const float*)d_in[11]; P.eln1b = (const float*)d_in[12];
  P.eln2g = (const float*)d_in[13]; P.eln2b = (const float*)d_in[14];
  P.elnfg = (const float*)d_in[15]; P.elnfb = (const float*)d_in[16];
  P.dqw  = (const float*)d_in[17]; P.dqb  = (const float*)d_in[18];
  P.dow  = (const float*)d_in[19]; P.dob  = (const float*)d_in[20];
  P.dxqw = (const float*)d_in[21]; P.dxqb = (const float*)d_in[22];
  P.dxow = (const float*)d_in[23]; P.dxob = (const float*)d_in[24];
  P.df1w = (const float*)d_in[25]; P.df1b = (const float*)d_in[26];
  P.df2w = (const float*)d_in[27]; P.df2b = (const float*)d_in[28];
  P.dln1g = (const float*)d_in[29]; P.dln1b = (const float*)d_in[30];
  P.dln2g = (const float*)d_in[31]; P.dln2b = (const float*)d_in[32];
  P.dln3g = (const float*)d_in[33]; P.dln3b = (const float*)d_in[34];
  P.dlnfg = (const float*)d_in[35]; P.dlnfb = (const float*)d_in[36];
  P.out = (float*)d_out;
  P.ws  = (float*)d_ws;
  // zero the grid-barrier counter (ws is poisoned 0xAA before every launch)
  hipMemsetAsync(d_ws, 0, 256, stream);
  hipLaunchKernelGGL(ar_transformer, dim3(NB), dim3(NT), 0, stream, P);
}

// Round 2
// 28825.977 us; speedup vs baseline: 2.7088x; 2.7088x over previous
//
#include <hip/hip_runtime.h>
#include <math.h>

// AutoregTransformer D=512 HID=2048 NH=8 L=4 T=32 B=16, fp32 in/out.
// Persistent kernel, 128 blocks x 512 threads, manual grid barrier.
// Decoder GEMMs: bf16 MFMA (16x16x32), fp32 accum/LN/softmax/residuals.
// Encoder + cross-attn precompute: fp32 vector (runs once, tiny).

#define NB 128
#define NT 512
#define Dm 512
#define HIDN 2048
#define TLEN 32
#define BSZ 16
#define NLAY 4

typedef unsigned int uint32;
typedef unsigned short u16;
typedef short bf16x8 __attribute__((ext_vector_type(8)));
typedef float f32x4 __attribute__((ext_vector_type(4)));

struct Params {
  const float* y; const float* start;
  const float *eqw, *eqb, *eow, *eob, *ef1w, *ef1b, *ef2w, *ef2b;
  const float *eln1g, *eln1b, *eln2g, *eln2b, *elnfg, *elnfb;
  const float *dqw, *dqb, *dow, *dob, *dxqw, *dxqb, *dxow, *dxob;
  const float *df1w, *df1b, *df2w, *df2b;
  const float *dln1g, *dln1b, *dln2g, *dln2b, *dln3g, *dln3b, *dlnfg, *dlnfb;
  float* out; float* ws;
};

__device__ __forceinline__ u16 f2b(float x) {
  uint32 u = __float_as_uint(x);
  u += 0x7fffu + ((u >> 16) & 1u);
  return (u16)(u >> 16);
}
__device__ __forceinline__ float b2f(u16 v) { return __uint_as_float(((uint32)v) << 16); }
__device__ __forceinline__ float dot4f(float4 a, float4 b) {
  return a.x*b.x + a.y*b.y + a.z*b.z + a.w*b.w;
}

struct AtnS { float Ks[32][65]; float Vs[32][65]; float Qs[16][65]; float P[16][33]; };
union Smem {
  struct { u16 Ob16[16][520]; union { AtnS at; float Of[16][512]; } u; } ac;
  struct { float As[8][512]; float Of8[8][512]; } enc;
  struct { float Of[16][512]; } ep;
};

// LayerNorm of one 512-wide row: 8 vals/lane over one 64-lane wave.
__device__ __forceinline__ void wave_ln(float v[8], const float* __restrict__ g,
                                        const float* __restrict__ bt, int cb) {
  float sum = 0.f, sq = 0.f;
#pragma unroll
  for (int q = 0; q < 8; ++q) { sum += v[q]; sq += v[q]*v[q]; }
#pragma unroll
  for (int m = 32; m; m >>= 1) { sum += __shfl_xor(sum, m, 64); sq += __shfl_xor(sq, m, 64); }
  float mean = sum * (1.f/Dm);
  float var  = sq  * (1.f/Dm) - mean*mean;
  float rs = rsqrtf(var + 1e-5f);
#pragma unroll
  for (int q = 0; q < 8; ++q) v[q] = (v[q]-mean)*rs*g[cb+q] + bt[cb+q];
}

// One wave computes a 16x64 bf16-MFMA tile: rows from A (row-major, lda elems),
// cols from W (row-major [N][K], pre-offset to col base). acc[cg] covers cols cg*16..+15.
template<int K>
__device__ __forceinline__ void wave_gemm(const u16* __restrict__ A, int lda,
                                          const u16* __restrict__ W, f32x4 acc[4]) {
  const int lane = threadIdx.x & 63;
  const int l15 = lane & 15, kg = lane >> 4;
  const u16* a = A + l15*lda + kg*8;
  const u16* w = W + (size_t)l15*K + kg*8;
#pragma unroll 4
  for (int kc = 0; kc < K/32; ++kc) {
    bf16x8 av = *(const bf16x8*)(a + kc*32);
#pragma unroll
    for (int cg = 0; cg < 4; ++cg) {
      bf16x8 bv = *(const bf16x8*)(w + (size_t)cg*16*K + kc*32);
      acc[cg] = __builtin_amdgcn_mfma_f32_16x16x32_bf16(av, bv, acc[cg], 0, 0, 0);
    }
  }
}

// fp32 encoder GEMM: 8 rows (rbase..rbase+7) x 512 cols (one col/thread), A stride == K.
template<int K>
__device__ void enc_gemm(const float* __restrict__ A, int rbase,
                         const float* __restrict__ W, const float* __restrict__ bias,
                         float acc[8], float (* __restrict__ As)[512]) {
  const int t = threadIdx.x;
#pragma unroll
  for (int r = 0; r < 8; ++r) acc[r] = 0.f;
  for (int kc = 0; kc < K/512; ++kc) {
    for (int i = t; i < 8*512; i += NT)
      As[i >> 9][i & 511] = A[(size_t)(rbase + (i >> 9))*K + kc*512 + (i & 511)];
    __syncthreads();
    const float4* w4 = (const float4*)(W + (size_t)t*K + kc*512);
    for (int k4 = 0; k4 < 128; ++k4) {
      float4 wv = w4[k4];
#pragma unroll
      for (int r = 0; r < 8; ++r) acc[r] += dot4f(((const float4*)As[r])[k4], wv);
    }
    __syncthreads();
  }
#pragma unroll
  for (int r = 0; r < 8; ++r) acc[r] += bias[t];
}

__device__ void convw(const float* __restrict__ s, u16* __restrict__ d, int n,
                      int gtid, int gs) {
  const float2* s2 = (const float2*)s;
  uint32* d2 = (uint32*)d;
  for (int i = gtid; i < n/2; i += gs) {
    float2 v = s2[i];
    d2[i] = (uint32)f2b(v.x) | ((uint32)f2b(v.y) << 16);
  }
}

#define GBAR() do {                                                              \
    __syncthreads(); ++epoch;                                                    \
    if (t == 0) {                                                                \
      __hip_atomic_fetch_add(cnt, 1u, __ATOMIC_RELEASE, __HIP_MEMORY_SCOPE_AGENT);\
      unsigned tgt_ = epoch * (unsigned)NB;                                      \
      while (__hip_atomic_load(cnt, __ATOMIC_RELAXED, __HIP_MEMORY_SCOPE_AGENT) < tgt_) \
        __builtin_amdgcn_s_sleep(2);                                             \
      __hip_atomic_load(cnt, __ATOMIC_ACQUIRE, __HIP_MEMORY_SCOPE_AGENT);        \
    }                                                                            \
    __syncthreads();                                                             \
  } while (0)

__global__ __launch_bounds__(NT) void ar_transformer(Params p) {
  __shared__ Smem sm;
  const int bid = blockIdx.x;
  const int t = threadIdx.x;
  const int wv = t >> 6, lane = t & 63, cb = lane * 8;
  const int l15 = lane & 15, kg = lane >> 4;
  unsigned epoch = 0;

  // ---- workspace carve ----
  float* f = p.ws;
  unsigned* cnt = (unsigned*)f;  f += 64;
  float* pe    = f; f += TLEN*Dm;
  float* xE    = f; f += 16*Dm;
  float* obE   = f; f += 16*Dm;
  float* h2E   = f; f += 16*Dm;
  float* uE    = f; f += 16*HIDN;
  float* membE = f; f += 16*Dm;
  float* vXE   = f; f += NLAY*16*Dm;
  float* crossE= f; f += NLAY*16*Dm;
  float* h0f   = f; f += BSZ*TLEN*Dm;
  float* hf    = f; f += BSZ*TLEN*Dm;
  float* h2f   = f; f += BSZ*TLEN*Dm;
  u16* us = (u16*)f;
  u16* h0b  = us; us += BSZ*TLEN*Dm;
  u16* hb   = us; us += BSZ*TLEN*Dm;
  u16* h2b  = us; us += BSZ*TLEN*Dm;
  u16* qkvb = us; us += BSZ*TLEN*3*Dm;
  u16* ub   = us; us += BSZ*TLEN*HIDN;
  u16* wq16 = us; us += NLAY*3*Dm*Dm;
  u16* wo16 = us; us += NLAY*Dm*Dm;
  u16* w116 = us; us += NLAY*HIDN*Dm;
  u16* w216 = us; us += NLAY*Dm*HIDN;

  const int gtid = bid*NT + t, gs = NB*NT;

  // ---- setup: weight conversion, pe, encoder input, h0 row 0 ----
  convw(p.dqw,  wq16, NLAY*3*Dm*Dm, gtid, gs);
  convw(p.dow,  wo16, NLAY*Dm*Dm,   gtid, gs);
  convw(p.df1w, w116, NLAY*HIDN*Dm, gtid, gs);
  convw(p.df2w, w216, NLAY*Dm*HIDN, gtid, gs);
  for (int i = gtid; i < TLEN*Dm; i += gs) {
    int tt = i >> 9, d = i & (Dm-1);
    int half = d >> 1;
    float ang = (float)tt * expf(-(float)(2*half) * (9.210340371976184f/512.0f));
    pe[i] = (d & 1) ? cosf(ang) : sinf(ang);
  }
  for (int i = gtid; i < 16*Dm; i += gs)
    xE[i] = p.y[i] + ((i & 1) ? 1.0f : 0.0f);
  for (int i = gtid; i < BSZ*Dm; i += gs) {
    int b = i >> 9, c = i & (Dm-1);
    float v0 = p.start[c] + ((c & 1) ? 1.0f : 0.0f);
    h0f[(size_t)(b*TLEN)*Dm + c] = v0;
    h0b[(size_t)(b*TLEN)*Dm + c] = f2b(v0);
  }
  GBAR();

  // ---- Encoder (fp32; S=1 so attn out == V) ----
  for (int l = 0; l < NLAY; ++l) {
    if (bid < 2) {            // V projection -> obE
      float acc[8];
      enc_gemm<Dm>(xE, bid*8, p.eqw + ((size_t)l*1536 + 1024)*Dm,
                   p.eqb + l*1536 + 1024, acc, sm.enc.As);
#pragma unroll
      for (int r = 0; r < 8; ++r) obE[(size_t)(bid*8+r)*Dm + t] = acc[r];
    }
    GBAR();
    if (bid < 2) {            // out proj + LN1 -> h2E
      float acc[8];
      enc_gemm<Dm>(obE, bid*8, p.eow + (size_t)l*Dm*Dm, p.eob + l*Dm, acc, sm.enc.As);
#pragma unroll
      for (int r = 0; r < 8; ++r) sm.enc.Of8[r][t] = acc[r];
      __syncthreads();
      int jr = wv;
      float v[8];
#pragma unroll
      for (int q = 0; q < 8; ++q) v[q] = xE[(size_t)(bid*8+jr)*Dm + cb+q] + sm.enc.Of8[jr][cb+q];
      wave_ln(v, p.eln1g + l*Dm, p.eln1b + l*Dm, cb);
#pragma unroll
      for (int q = 0; q < 8; ++q) h2E[(size_t)(bid*8+jr)*Dm + cb+q] = v[q];
    }
    GBAR();
    if (bid < 8) {            // FFN1 -> uE
      int rh = bid & 1, ncg = bid >> 1;
      float acc[8];
      enc_gemm<Dm>(h2E, rh*8, p.ef1w + ((size_t)l*HIDN + ncg*Dm)*Dm,
                   p.ef1b + l*HIDN + ncg*Dm, acc, sm.enc.As);
#pragma unroll
      for (int r = 0; r < 8; ++r) {
        float u = acc[r];
        u = 0.5f*u*(1.0f + erff(u*0.70710678118654752f));
        uE[(size_t)(rh*8+r)*HIDN + ncg*Dm + t] = u;
      }
    }
    GBAR();
    if (bid < 2) {            // FFN2 + LN2 -> xE
      float acc[8];
      enc_gemm<HIDN>(uE, bid*8, p.ef2w + (size_t)l*Dm*HIDN, p.ef2b + l*Dm, acc, sm.enc.As);
#pragma unroll
      for (int r = 0; r < 8; ++r) sm.enc.Of8[r][t] = acc[r];
      __syncthreads();
      int jr = wv;
      float v[8];
#pragma unroll
      for (int q = 0; q < 8; ++q) v[q] = h2E[(size_t)(bid*8+jr)*Dm + cb+q] + sm.enc.Of8[jr][cb+q];
      wave_ln(v, p.eln2g + l*Dm, p.eln2b + l*Dm, cb);
#pragma unroll
      for (int q = 0; q < 8; ++q) xE[(size_t)(bid*8+jr)*Dm + cb+q] = v[q];
    }
    GBAR();
  }
  if (bid == 0) {             // final encoder LN -> membE
    for (int r = wv; r < 16; r += 8) {
      float v[8];
#pragma unroll
      for (int q = 0; q < 8; ++q) v[q] = xE[(size_t)r*Dm + cb+q];
      wave_ln(v, p.elnfg, p.elnfb, cb);
#pragma unroll
      for (int q = 0; q < 8; ++q) membE[(size_t)r*Dm + cb+q] = v[q];
    }
  }
  GBAR();
  if (bid < 8) {              // cross-attn V: vXE[l] = mem @ Wxv^T + bxv
    int l2 = bid >> 1, rh = bid & 1;
    float acc[8];
    enc_gemm<Dm>(membE, rh*8, p.dxqw + ((size_t)l2*1536 + 1024)*Dm,
                 p.dxqb + l2*1536 + 1024, acc, sm.enc.As);
#pragma unroll
    for (int r = 0; r < 8; ++r) vXE[(size_t)(l2*16 + rh*8 + r)*Dm + t] = acc[r];
  }
  GBAR();
  if (bid < 8) {              // cross[l] = vXE[l] @ Wxo^T + bxo
    int l2 = bid >> 1, rh = bid & 1;
    float acc[8];
    enc_gemm<Dm>(vXE + (size_t)l2*16*Dm, rh*8, p.dxow + (size_t)l2*Dm*Dm,
                 p.dxob + l2*Dm, acc, sm.enc.As);
#pragma unroll
    for (int r = 0; r < 8; ++r) crossE[(size_t)(l2*16 + rh*8 + r)*Dm + t] = acc[r];
  }
  GBAR();

  // ---- Autoregressive decode ----
  for (int st = 0; st < TLEN; ++st) {
    const int s = st + 1;
    const int JT = (s + 15) >> 4;
    const int jtL = (s - 1) >> 4;
    for (int l = 0; l < NLAY; ++l) {
      const u16* Asrc = (l == 0) ? h0b : hb;
      const u16* wq16l = wq16 + (size_t)l*1536*Dm;
      const float* qbl = p.dqb + l*1536;
      // ---- Q: QKV GEMM -> qkvb ----
      {
        int items = 16*JT*3;
        if (bid < items) {
          int ng = bid % 3, rem = bid/3, jt = rem % JT, b = rem / JT;
          int c0 = ng*512 + wv*64;
          const u16* A = Asrc + (size_t)(b*TLEN + jt*16)*Dm;
          f32x4 acc[4] = {};
          wave_gemm<Dm>(A, Dm, wq16l + (size_t)c0*Dm, acc);
#pragma unroll
          for (int cg = 0; cg < 4; ++cg) {
            int col = c0 + cg*16 + l15;
            float bias = qbl[col];
#pragma unroll
            for (int r = 0; r < 4; ++r) {
              int j = jt*16 + kg*4 + r;
              if (j < s) {
                float v = acc[cg][r] + bias;
                if (col < 512) v *= 0.125f;
                qkvb[(size_t)(b*TLEN + j)*1536 + col] = f2b(v);
              }
            }
          }
        }
      }
      GBAR();
      // ---- AC: self-attn + out proj + LN1 + cross + LN2 -> h2 ----
      {
        int JTe = (l == NLAY-1) ? 1 : JT;
        int items = 16*JTe;
        if (bid < items) {
          int jt = (l == NLAY-1) ? jtL : (bid % JTe);
          int b = bid / JTe;
          AtnS& at = sm.ac.u.at;
          for (int h = 0; h < 8; ++h) {
            for (int i = t; i < s*64; i += NT) {
              int j2 = i >> 6, d = i & 63;
              at.Ks[j2][d] = b2f(qkvb[(size_t)(b*TLEN+j2)*1536 +  512 + h*64 + d]);
              at.Vs[j2][d] = b2f(qkvb[(size_t)(b*TLEN+j2)*1536 + 1024 + h*64 + d]);
            }
            for (int i = t; i < 16*64; i += NT) {
              int r = i >> 6, d = i & 63;
              at.Qs[r][d] = b2f(qkvb[(size_t)(b*TLEN + jt*16 + r)*1536 + h*64 + d]);
            }
            __syncthreads();
            {
              int j = t >> 5, j2 = t & 31;
              if (j2 < s) {
                float a = 0.f;
#pragma unroll
                for (int k = 0; k < 64; ++k) a += at.Qs[j][k] * at.Ks[j2][k];
                at.P[j][j2] = a;
              }
            }
            __syncthreads();
            for (int jr = wv; jr < 16; jr += 8) {
              float sv = (lane < s) ? at.P[jr][lane] : -3.0e38f;
              float mx = sv;
#pragma unroll
              for (int m = 32; m; m >>= 1) mx = fmaxf(mx, __shfl_xor(mx, m, 64));
              float e = (lane < s) ? expf(sv - mx) : 0.f;
              float sum = e;
#pragma unroll
              for (int m = 32; m; m >>= 1) sum += __shfl_xor(sum, m, 64);
              if (lane < s) at.P[jr][lane] = e / sum;
            }
            __syncthreads();
            {
              int j = t >> 5, d0 = (t & 31)*2;
              float a0 = 0.f, a1 = 0.f;
              for (int j2 = 0; j2 < s; ++j2) {
                float pp = at.P[j][j2];
                a0 += pp * at.Vs[j2][d0];
                a1 += pp * at.Vs[j2][d0+1];
              }
              sm.ac.Ob16[j][h*64 + d0]   = f2b(a0);
              sm.ac.Ob16[j][h*64 + d0+1] = f2b(a1);
            }
            __syncthreads();
          }
          // out proj from LDS Ob16
          f32x4 acc[4] = {};
          wave_gemm<Dm>(&sm.ac.Ob16[0][0], 520,
                        wo16 + ((size_t)l*Dm + wv*64)*Dm, acc);
          __syncthreads();   // all reads of at/Ob16 done before Of overwrites union
#pragma unroll
          for (int cg = 0; cg < 4; ++cg) {
            int col = wv*64 + cg*16 + l15;
            float bias = p.dob[l*Dm + col];
#pragma unroll
            for (int r = 0; r < 4; ++r)
              sm.ac.u.Of[kg*4 + r][col] = acc[cg][r] + bias;
          }
          __syncthreads();
          const float* xin = (l == 0) ? h0f : hf;
          for (int jr = wv; jr < 16; jr += 8) {
            int j = jt*16 + jr;
            size_t g = (size_t)(b*TLEN + j);
            float v[8];
#pragma unroll
            for (int q = 0; q < 8; ++q) v[q] = xin[g*Dm + cb+q] + sm.ac.u.Of[jr][cb+q];
            wave_ln(v, p.dln1g + l*Dm, p.dln1b + l*Dm, cb);
#pragma unroll
            for (int q = 0; q < 8; ++q) v[q] += crossE[(size_t)(l*16 + b)*Dm + cb+q];
            wave_ln(v, p.dln2g + l*Dm, p.dln2b + l*Dm, cb);
            if (j < s) {
#pragma unroll
              for (int q = 0; q < 8; ++q) {
                h2f[g*Dm + cb+q] = v[q];
                h2b[g*Dm + cb+q] = f2b(v[q]);
              }
            }
          }
        }
      }
      GBAR();
      // ---- D: FFN1 -> ub ----
      {
        int JTe = (l == NLAY-1) ? 1 : JT;
        int items = 16*JTe*4;
        if (bid < items) {
          int ng = bid & 3, rem = bid >> 2;
          int jt = (l == NLAY-1) ? jtL : (rem % JTe);
          int b = (l == NLAY-1) ? rem : (rem / JTe);
          int c0 = ng*512 + wv*64;
          const u16* A = h2b + (size_t)(b*TLEN + jt*16)*Dm;
          f32x4 acc[4] = {};
          wave_gemm<Dm>(A, Dm, w116 + ((size_t)l*HIDN + c0)*Dm, acc);
#pragma unroll
          for (int cg = 0; cg < 4; ++cg) {
            int col = c0 + cg*16 + l15;
            float bias = p.df1b[l*HIDN + col];
#pragma unroll
            for (int r = 0; r < 4; ++r) {
              int j = jt*16 + kg*4 + r;
              if (j < s) {
                float u = acc[cg][r] + bias;
                u = 0.5f*u*(1.0f + erff(u*0.70710678118654752f));
                ub[(size_t)(b*TLEN + j)*HIDN + col] = f2b(u);
              }
            }
          }
        }
      }
      GBAR();
      // ---- E: FFN2 + LN3 -> hf/hb  (+ final LN, token append, h0 update) ----
      {
        int JTe = (l == NLAY-1) ? 1 : JT;
        int items = 16*JTe;
        if (bid < items) {
          int jt = (l == NLAY-1) ? jtL : (bid % JTe);
          int b = bid / JTe;
          const u16* A = ub + (size_t)(b*TLEN + jt*16)*HIDN;
          f32x4 acc[4] = {};
          wave_gemm<HIDN>(A, HIDN, w216 + ((size_t)l*Dm + wv*64)*HIDN, acc);
#pragma unroll
          for (int cg = 0; cg < 4; ++cg) {
            int col = wv*64 + cg*16 + l15;
            float bias = p.df2b[l*Dm + col];
#pragma unroll
            for (int r = 0; r < 4; ++r)
              sm.ep.Of[kg*4 + r][col] = acc[cg][r] + bias;
          }
          __syncthreads();
          for (int jr = wv; jr < 16; jr += 8) {
            int j = jt*16 + jr;
            size_t g = (size_t)(b*TLEN + j);
            float v[8];
#pragma unroll
            for (int q = 0; q < 8; ++q) v[q] = h2f[g*Dm + cb+q] + sm.ep.Of[jr][cb+q];
            wave_ln(v, p.dln3g + l*Dm, p.dln3b + l*Dm, cb);
            if (j < s) {
#pragma unroll
              for (int q = 0; q < 8; ++q) {
                hf[g*Dm + cb+q] = v[q];
                hb[g*Dm + cb+q] = f2b(v[q]);
              }
            }
            if (l == NLAY-1 && j == s-1) {
              wave_ln(v, p.dlnfg, p.dlnfb, cb);
#pragma unroll
              for (int q = 0; q < 8; ++q) {
                float ov = v[q];
                p.out[(size_t)(b*TLEN + st)*Dm + cb+q] = ov;
                if (st + 1 < TLEN) {
                  float nh = ov + pe[(size_t)(st+1)*Dm + cb+q];
                  h0f[(size_t)(b*TLEN + st+1)*Dm + cb+q] = nh;
                  h0b[(size_t)(b*TLEN + st+1)*Dm + cb+q] = f2b(nh);
                }
              }
            }
          }
        }
      }
      GBAR();
    }
  }
}

extern "C" void kernel_launch(void* const* d_in, const int* in_sizes, int n_in,
                              void* d_out, int out_size, void* d_ws, size_t ws_size,
                              hipStream_t stream) {
  Params P;
  P.y     = (const float*)d_in[0];
  P.start = (const float*)d_in[1];
  // d_in[2] = target_length (fixed 32)
  P.eqw  = (const float*)d_in[3];  P.eqb  = (const float*)d_in[4];
  P.eow  = (const float*)d_in[5];  P.eob  = (const float*)d_in[6];
  P.ef1w = (const float*)d_in[7];  P.ef1b = (const float*)d_in[8];
  P.ef2w = (const float*)d_in[9];  P.ef2b = (const float*)d_in[10];
  P.eln1g = (const float*)d_in[11]; P.eln1b = (const float*)d_in[12];
  P.eln2g = (const float*)d_in[13]; P.eln2b = (const float*)d_in[14];
  P.elnfg = (const float*)d_in[15]; P.elnfb = (const float*)d_in[16];
  P.dqw  = (const float*)d_in[17]; P.dqb  = (const float*)d_in[18];
  P.dow  = (const float*)d_in[19]; P.dob  = (const float*)d_in[20];
  P.dxqw = (const float*)d_in[21]; P.dxqb = (const float*)d_in[22];
  P.dxow = (const float*)d_in[23]; P.dxob = (const float*)d_in[24];
  P.df1w = (const float*)d_in[25]; P.df1b = (const float*)d_in[26];
  P.df2w = (const float*)d_in[27]; P.df2b = (const float*)d_in[28];
  P.dln1g = (const float*)d_in[29]; P.dln1b = (const float*)d_in[30];
  P.dln2g = (const float*)d_in[31]; P.dln2b = (const float*)d_in[32];
  P.dln3g = (const float*)d_in[33]; P.dln3b = (const float*)d_in[34];
  P.dlnfg = (const float*)d_in[35]; P.dlnfb = (const float*)d_in[36];
  P.out = (float*)d_out;
  P.ws  = (float*)d_ws;
  hipMemsetAsync(d_ws, 0, 256, stream);   // zero grid-barrier counter
  hipLaunchKernelGGL(ar_transformer, dim3(NB), dim3(NT), 0, stream, P);
}

// Round 3
// 22308.440 us; speedup vs baseline: 3.5002x; 1.2922x over previous
//
#include <hip/hip_runtime.h>
#include <math.h>

// AutoregTransformer D=512 HID=2048 NH=8 L=4 T=32 B=16, fp32 in/out.
// 16 independent groups (one per batch) x 8 blocks x 512 threads.
// Group-local barriers only (8 participants). Blocks of group g have
// bid % 16 == g -> same XCD under round-robin dispatch (perf heuristic).
// Decoder GEMMs + attention: bf16 MFMA 16x16x32, fp32 accum/LN/softmax.

#define NB 128
#define NT 512
#define GM 8
#define NGRP 16
#define Dm 512
#define HIDN 2048
#define TLEN 32
#define BSZ 16
#define NLAY 4
#define PBF 147968   // floats per batch region

typedef unsigned int uint32;
typedef unsigned short u16;
typedef short bf16x8 __attribute__((ext_vector_type(8)));
typedef float f32x4 __attribute__((ext_vector_type(4)));

struct Params {
  const float* y; const float* start;
  const float *eqw, *eqb, *eow, *eob, *ef1w, *ef1b, *ef2w, *ef2b;
  const float *eln1g, *eln1b, *eln2g, *eln2b, *elnfg, *elnfb;
  const float *dqw, *dqb, *dow, *dob, *dxqw, *dxqb, *dxow, *dxob;
  const float *df1w, *df1b, *df2w, *df2b;
  const float *dln1g, *dln1b, *dln2g, *dln2b, *dln3g, *dln3b, *dlnfg, *dlnfb;
  float* out; float* ws;
};

__device__ __forceinline__ u16 f2b(float x) {
  uint32 u = __float_as_uint(x);
  u += 0x7fffu + ((u >> 16) & 1u);
  return (u16)(u >> 16);
}
__device__ __forceinline__ float dot4f(float4 a, float4 b) {
  return a.x*b.x + a.y*b.y + a.z*b.z + a.w*b.w;
}

struct DecS {
  u16 P[8][512];        // per-head P (16 rows x 32 keys) bf16
  u16 Ob[16][520];      // attn output tile bf16 (pad 8)
  float Of[16][516];    // fp32 staging for LN (pad 4)
};
struct EncS { float xn[2048]; };
union Smem { DecS d; EncS e; };

// LayerNorm of one 512-wide row held 8 vals/lane across one 64-lane wave.
__device__ __forceinline__ void wave_ln(float v[8], const float* __restrict__ g,
                                        const float* __restrict__ bt, int cb) {
  float sum = 0.f, sq = 0.f;
#pragma unroll
  for (int q = 0; q < 8; ++q) { sum += v[q]; sq += v[q]*v[q]; }
#pragma unroll
  for (int m = 32; m; m >>= 1) { sum += __shfl_xor(sum, m, 64); sq += __shfl_xor(sq, m, 64); }
  float mean = sum * (1.f/Dm);
  float var  = sq  * (1.f/Dm) - mean*mean;
  float rs = rsqrtf(var + 1e-5f);
#pragma unroll
  for (int q = 0; q < 8; ++q) v[q] = (v[q]-mean)*rs*g[cb+q] + bt[cb+q];
}

// One wave: 16 x 64 tile, A row-major [16][K] (lda=K), W row-major [N][K].
template<int K>
__device__ __forceinline__ void wave_gemm(const u16* __restrict__ A,
                                          const u16* __restrict__ W, f32x4 acc[4]) {
  const int lane = threadIdx.x & 63;
  const int l15 = lane & 15, kg = lane >> 4;
  const u16* a = A + (size_t)l15*K + kg*8;
  const u16* w = W + (size_t)l15*K + kg*8;
#pragma unroll 4
  for (int kc = 0; kc < K/32; ++kc) {
    bf16x8 av = *(const bf16x8*)(a + kc*32);
#pragma unroll
    for (int cg = 0; cg < 4; ++cg) {
      bf16x8 bv = *(const bf16x8*)(w + (size_t)cg*16*K + kc*32);
      acc[cg] = __builtin_amdgcn_mfma_f32_16x16x32_bf16(av, bv, acc[cg], 0, 0, 0);
    }
  }
}

__device__ __forceinline__ float dotn(const float* __restrict__ xn,
                                      const float* __restrict__ w, int n4) {
  const float4* x4 = (const float4*)xn;
  const float4* w4 = (const float4*)w;
  float a = 0.f;
#pragma unroll 8
  for (int k = 0; k < n4; ++k) a += dot4f(x4[k], w4[k]);
  return a;
}

__device__ void convw(const float* __restrict__ s, u16* __restrict__ d, int n,
                      int gtid, int gs) {
  const float2* s2 = (const float2*)s;
  uint32* d2 = (uint32*)d;
  for (int i = gtid; i < n/2; i += gs) {
    float2 v = s2[i];
    d2[i] = (uint32)f2b(v.x) | ((uint32)f2b(v.y) << 16);
  }
}

#define BAR(cp, n, ep) do {                                                       \
    __syncthreads();                                                              \
    if (t == 0) {                                                                 \
      __hip_atomic_fetch_add((cp), 1u, __ATOMIC_RELEASE, __HIP_MEMORY_SCOPE_AGENT);\
      ++(ep);                                                                     \
      unsigned tg_ = (ep) * (unsigned)(n);                                        \
      while (__hip_atomic_load((cp), __ATOMIC_RELAXED, __HIP_MEMORY_SCOPE_AGENT) < tg_) \
        __builtin_amdgcn_s_sleep(2);                                              \
      (void)__hip_atomic_load((cp), __ATOMIC_ACQUIRE, __HIP_MEMORY_SCOPE_AGENT);  \
    }                                                                             \
    __syncthreads();                                                              \
  } while (0)

__global__ __launch_bounds__(NT) void ar_transformer(Params p) {
  __shared__ Smem sm;
  const int bid = blockIdx.x;
  const int t = threadIdx.x;
  const int g = bid & 15;        // group == batch
  const int m = bid >> 4;        // member 0..7
  const int b = g;
  const int wv = t >> 6, lane = t & 63, cb = lane * 8;
  const int l15 = lane & 15, kg = lane >> 4;
  unsigned epA = 0, epG = 0;

  unsigned* cbase = (unsigned*)p.ws;
  unsigned* cntA = cbase;
  unsigned* cntG = cbase + 16 + g*16;
  float* f = p.ws + 1024;
  float* pe = f;            f += TLEN*Dm;
  float* batch0 = f;        f += (size_t)NGRP * PBF;
  u16* wq16 = (u16*)f;
  u16* wo16 = wq16 + (size_t)NLAY*1536*512;
  u16* w116 = wo16 + (size_t)NLAY*512*512;
  u16* w216 = w116 + (size_t)NLAY*2048*512;

  float* bb = batch0 + (size_t)b * PBF;
  float* xrow = bb, *arow = bb+512, *ofrow = bb+1024, *h2row = bb+1536, *frow = bb+2048;
  float* urow = bb+2560, *vxall = bb+4608, *crossE = bb+6656;
  float* h0f = bb+8704, *hf = bb+25088, *h2f = bb+41472;
  u16* ub16 = (u16*)(bb + 57856);
  u16* h0b  = ub16;
  u16* hb   = h0b + 16384;
  u16* h2b  = hb + 16384;
  u16* qkvb = h2b + 16384;
  u16* ubuf = qkvb + 49152;
  u16* vt   = ubuf + 65536;     // [8 heads][64 d][32 keys] bf16 (V transposed)

  const int gtid = bid*NT + t, gs = NB*NT;

  // ---------- init (all blocks) ----------
  convw(p.dqw,  wq16, NLAY*1536*512, gtid, gs);
  convw(p.dow,  wo16, NLAY*512*512,  gtid, gs);
  convw(p.df1w, w116, NLAY*2048*512, gtid, gs);
  convw(p.df2w, w216, NLAY*512*2048, gtid, gs);
  for (int i = gtid; i < TLEN*Dm; i += gs) {
    int tt = i >> 9, d = i & (Dm-1);
    int half = d >> 1;
    float ang = (float)tt * expf(-(float)(2*half) * (9.210340371976184f/512.0f));
    pe[i] = (d & 1) ? cosf(ang) : sinf(ang);
  }
  for (int i = gtid; i < BSZ*Dm; i += gs) {
    int bI = i >> 9, c = i & (Dm-1);
    float* bbI = batch0 + (size_t)bI*PBF;
    bbI[c] = p.y[i] + ((c & 1) ? 1.0f : 0.0f);          // x0 = y + pe0
    float v0 = p.start[c] + ((c & 1) ? 1.0f : 0.0f);
    bbI[8704 + c] = v0;                                  // h0f row 0
    ((u16*)(bbI + 57856))[c] = f2b(v0);                  // h0b row 0
  }
  BAR(cntA, NB, epA);

  // ---------- encoder (group-local; seq_len=1 so attn out == V) ----------
  for (int l = 0; l < NLAY; ++l) {
    // P1: V projection.  input = (l==0) ? x0 : LN2(h2row+frow)
    if (l == 0) {
      for (int i = t; i < 512; i += NT) sm.e.xn[i] = xrow[i];
    } else if (wv == 0) {
      float v[8];
#pragma unroll
      for (int q = 0; q < 8; ++q) v[q] = h2row[cb+q] + frow[cb+q];
      wave_ln(v, p.eln2g + (l-1)*Dm, p.eln2b + (l-1)*Dm, cb);
#pragma unroll
      for (int q = 0; q < 8; ++q) sm.e.xn[cb+q] = v[q];
      if (m == 0)
#pragma unroll
        for (int q = 0; q < 8; ++q) xrow[cb+q] = v[q];
    }
    __syncthreads();
    if (t < 64) {
      int c = m*64 + t;
      arow[c] = dotn(sm.e.xn, p.eqw + ((size_t)l*1536 + 1024 + c)*512, 128)
                + p.eqb[l*1536 + 1024 + c];
    }
    BAR(cntG, GM, epG);
    // P2: out proj
    for (int i = t; i < 512; i += NT) sm.e.xn[i] = arow[i];
    __syncthreads();
    if (t < 64) {
      int c = m*64 + t;
      ofrow[c] = dotn(sm.e.xn, p.eow + ((size_t)l*512 + c)*512, 128) + p.eob[l*512 + c];
    }
    BAR(cntG, GM, epG);
    // P3: LN1 + FFN1
    if (wv == 0) {
      float v[8];
#pragma unroll
      for (int q = 0; q < 8; ++q) v[q] = xrow[cb+q] + ofrow[cb+q];
      wave_ln(v, p.eln1g + l*Dm, p.eln1b + l*Dm, cb);
#pragma unroll
      for (int q = 0; q < 8; ++q) sm.e.xn[cb+q] = v[q];
      if (m == 0)
#pragma unroll
        for (int q = 0; q < 8; ++q) h2row[cb+q] = v[q];
    }
    __syncthreads();
    if (t < 256) {
      int c = m*256 + t;
      float u = dotn(sm.e.xn, p.ef1w + ((size_t)l*2048 + c)*512, 128) + p.ef1b[l*2048 + c];
      u = 0.5f*u*(1.0f + erff(u*0.70710678118654752f));
      urow[c] = u;
    }
    BAR(cntG, GM, epG);
    // P4: FFN2
    for (int i = t; i < 2048; i += NT) sm.e.xn[i] = urow[i];
    __syncthreads();
    if (t < 64) {
      int c = m*64 + t;
      frow[c] = dotn(sm.e.xn, p.ef2w + ((size_t)l*512 + c)*2048, 512) + p.ef2b[l*512 + c];
    }
    BAR(cntG, GM, epG);
  }
  // PF1: mem = LNf(LN2(h2row+frow)); cross-V for all 4 layers
  if (wv == 0) {
    float v[8];
#pragma unroll
    for (int q = 0; q < 8; ++q) v[q] = h2row[cb+q] + frow[cb+q];
    wave_ln(v, p.eln2g + 3*Dm, p.eln2b + 3*Dm, cb);
    wave_ln(v, p.elnfg, p.elnfb, cb);
#pragma unroll
    for (int q = 0; q < 8; ++q) sm.e.xn[cb+q] = v[q];
  }
  __syncthreads();
  if (t < 256) {
    int cc = m*256 + t, lc = cc >> 9, c = cc & 511;
    vxall[cc] = dotn(sm.e.xn, p.dxqw + ((size_t)lc*1536 + 1024 + c)*512, 128)
                + p.dxqb[lc*1536 + 1024 + c];
  }
  BAR(cntG, GM, epG);
  // PF2: cross = vx @ Wxo^T + bxo (per layer)
  for (int i = t; i < 2048; i += NT) sm.e.xn[i] = vxall[i];
  __syncthreads();
  if (t < 256) {
    int cc = m*256 + t, lc = cc >> 9, c = cc & 511;
    crossE[cc] = dotn(sm.e.xn + lc*512, p.dxow + ((size_t)lc*512 + c)*512, 128)
                 + p.dxob[lc*512 + c];
  }
  BAR(cntG, GM, epG);

  // ---------- autoregressive decode (group-local) ----------
  for (int st = 0; st < TLEN; ++st) {
    const int s = st + 1;
    const int JT = (s + 15) >> 4;
    const int jtL = (s - 1) >> 4;
    for (int l = 0; l < NLAY; ++l) {
      // ---- Q: QKV GEMM; V stored transposed into vt ----
      {
        const u16* Asrc = (l == 0) ? h0b : hb;
        int ntile = JT*24, tid = m*8 + wv;
        if (tid < ntile) {
          int jt = tid/24, c24 = tid%24, c0 = c24*64;
          f32x4 acc[4] = {};
          wave_gemm<512>(Asrc + (size_t)jt*16*512, wq16 + ((size_t)l*1536 + c0)*512, acc);
#pragma unroll
          for (int cg = 0; cg < 4; ++cg) {
            int col = c0 + cg*16 + l15;
            float bias = p.dqb[l*1536 + col];
#pragma unroll
            for (int r = 0; r < 4; ++r) {
              int j = jt*16 + kg*4 + r;
              if (j < s) {
                float v = acc[cg][r] + bias;
                if (col < 512)       qkvb[(size_t)j*1536 + col] = f2b(v * 0.125f);
                else if (col < 1024) qkvb[(size_t)j*1536 + col] = f2b(v);
                else {
                  int d = col - 1024;
                  vt[(size_t)((d >> 6)*64 + (d & 63))*32 + j] = f2b(v);
                }
              }
            }
          }
        }
      }
      BAR(cntG, GM, epG);
      // ---- ATN: 8 heads in parallel (wave=head) + out proj + LN1 + cross + LN2 ----
      {
        bool act; int jt;
        if (l == NLAY-1) { act = (m == 0); jt = jtL; }
        else             { act = (m < JT); jt = m;   }
        if (act) {
          const int h = wv;
          // scores: A=Q rows, B=K keys (both from qkvb)
          f32x4 sc[2] = {};
          const u16* qA = qkvb + (size_t)(jt*16 + l15)*1536 + h*64 + kg*8;
          const u16* kB = qkvb + 512 + h*64 + kg*8;
#pragma unroll
          for (int ks = 0; ks < 2; ++ks) {
            bf16x8 av = *(const bf16x8*)(qA + ks*32);
#pragma unroll
            for (int cg = 0; cg < 2; ++cg) {
              bf16x8 bv = *(const bf16x8*)(kB + (size_t)(cg*16 + l15)*1536 + ks*32);
              sc[cg] = __builtin_amdgcn_mfma_f32_16x16x32_bf16(av, bv, sc[cg], 0, 0, 0);
            }
          }
          // softmax per row (cols spread over 16 lanes x 2 cg)
#pragma unroll
          for (int r = 0; r < 4; ++r) {
            float v0 = (l15      < s) ? sc[0][r] : -3.0e38f;
            float v1 = (l15 + 16 < s) ? sc[1][r] : -3.0e38f;
            float mx = fmaxf(v0, v1);
#pragma unroll
            for (int mk = 1; mk < 16; mk <<= 1) mx = fmaxf(mx, __shfl_xor(mx, mk, 64));
            float e0 = expf(v0 - mx), e1 = expf(v1 - mx);
            float sum = e0 + e1;
#pragma unroll
            for (int mk = 1; mk < 16; mk <<= 1) sum += __shfl_xor(sum, mk, 64);
            float inv = 1.0f / sum;
            int row = kg*4 + r;
            sm.d.P[h][row*32 + l15]      = f2b(e0 * inv);
            sm.d.P[h][row*32 + 16 + l15] = f2b(e1 * inv);
          }
          __syncthreads();
          // P @ V  (A = P, B = vt)
          f32x4 ov[4] = {};
          bf16x8 pa = *(const bf16x8*)&sm.d.P[h][l15*32 + kg*8];
#pragma unroll
          for (int cg = 0; cg < 4; ++cg) {
            bf16x8 bv = *(const bf16x8*)(vt + (size_t)(h*64 + cg*16 + l15)*32 + kg*8);
            ov[cg] = __builtin_amdgcn_mfma_f32_16x16x32_bf16(pa, bv, ov[cg], 0, 0, 0);
          }
#pragma unroll
          for (int cg = 0; cg < 4; ++cg)
#pragma unroll
            for (int r = 0; r < 4; ++r)
              sm.d.Ob[kg*4 + r][h*64 + cg*16 + l15] = f2b(ov[cg][r]);
          __syncthreads();
          // out proj (A = Ob in LDS, B = wo16)
          f32x4 oc[4] = {};
          int c0 = wv*64;
          const u16* wB = wo16 + ((size_t)l*512 + c0 + l15)*512 + kg*8;
#pragma unroll 4
          for (int ks = 0; ks < 16; ++ks) {
            bf16x8 av = *(const bf16x8*)&sm.d.Ob[l15][kg*8 + ks*32];
#pragma unroll
            for (int cg = 0; cg < 4; ++cg) {
              bf16x8 bv = *(const bf16x8*)(wB + (size_t)cg*16*512 + ks*32);
              oc[cg] = __builtin_amdgcn_mfma_f32_16x16x32_bf16(av, bv, oc[cg], 0, 0, 0);
            }
          }
#pragma unroll
          for (int cg = 0; cg < 4; ++cg) {
            int col = c0 + cg*16 + l15;
            float bias = p.dob[l*512 + col];
#pragma unroll
            for (int r = 0; r < 4; ++r)
              sm.d.Of[kg*4 + r][col] = oc[cg][r] + bias;
          }
          __syncthreads();
          const float* xin = (l == 0) ? h0f : hf;
          for (int jr = wv; jr < 16; jr += 8) {
            int j = jt*16 + jr;
            float v[8];
#pragma unroll
            for (int q = 0; q < 8; ++q) v[q] = xin[(size_t)j*512 + cb+q] + sm.d.Of[jr][cb+q];
            wave_ln(v, p.dln1g + l*512, p.dln1b + l*512, cb);
#pragma unroll
            for (int q = 0; q < 8; ++q) v[q] += crossE[l*512 + cb+q];
            wave_ln(v, p.dln2g + l*512, p.dln2b + l*512, cb);
            if (j < s) {
#pragma unroll
              for (int q = 0; q < 8; ++q) {
                h2f[(size_t)j*512 + cb+q] = v[q];
                h2b[(size_t)j*512 + cb+q] = f2b(v[q]);
              }
            }
          }
        }
      }
      BAR(cntG, GM, epG);
      // ---- F1: FFN1 + gelu ----
      {
        int ntile = (l == NLAY-1) ? 32 : JT*32;
        int tid = m*8 + wv;
        if (tid < ntile) {
          int jt, c;
          if (l == NLAY-1) { jt = jtL; c = tid; } else { jt = tid >> 5; c = tid & 31; }
          f32x4 acc[4] = {};
          wave_gemm<512>(h2b + (size_t)jt*16*512, w116 + ((size_t)l*2048 + c*64)*512, acc);
#pragma unroll
          for (int cg = 0; cg < 4; ++cg) {
            int col = c*64 + cg*16 + l15;
            float bias = p.df1b[l*2048 + col];
#pragma unroll
            for (int r = 0; r < 4; ++r) {
              int j = jt*16 + kg*4 + r;
              if (j < s) {
                float u = acc[cg][r] + bias;
                u = 0.5f*u*(1.0f + erff(u*0.70710678118654752f));
                ubuf[(size_t)j*2048 + col] = f2b(u);
              }
            }
          }
        }
      }
      BAR(cntG, GM, epG);
      // ---- F2: FFN2 + LN3 (+ final LN, output, h0 update) ----
      {
        bool act; int jt;
        if (l == NLAY-1) { act = (m == 0); jt = jtL; }
        else             { act = (m < JT); jt = m;   }
        if (act) {
          f32x4 acc[4] = {};
          int c0 = wv*64;
          wave_gemm<2048>(ubuf + (size_t)jt*16*2048, w216 + ((size_t)l*512 + c0)*2048, acc);
#pragma unroll
          for (int cg = 0; cg < 4; ++cg) {
            int col = c0 + cg*16 + l15;
            float bias = p.df2b[l*512 + col];
#pragma unroll
            for (int r = 0; r < 4; ++r)
              sm.d.Of[kg*4 + r][col] = acc[cg][r] + bias;
          }
          __syncthreads();
          for (int jr = wv; jr < 16; jr += 8) {
            int j = jt*16 + jr;
            float v[8];
#pragma unroll
            for (int q = 0; q < 8; ++q) v[q] = h2f[(size_t)j*512 + cb+q] + sm.d.Of[jr][cb+q];
            wave_ln(v, p.dln3g + l*512, p.dln3b + l*512, cb);
            if (j < s) {
#pragma unroll
              for (int q = 0; q < 8; ++q) {
                hf[(size_t)j*512 + cb+q] = v[q];
                hb[(size_t)j*512 + cb+q] = f2b(v[q]);
              }
            }
            if (l == NLAY-1 && j == s-1) {
              wave_ln(v, p.dlnfg, p.dlnfb, cb);
#pragma unroll
              for (int q = 0; q < 8; ++q) {
                float ov = v[q];
                p.out[(size_t)(b*TLEN + st)*512 + cb+q] = ov;
                if (st + 1 < TLEN) {
                  float nh = ov + pe[(size_t)(st+1)*512 + cb+q];
                  h0f[(size_t)(st+1)*512 + cb+q] = nh;
                  h0b[(size_t)(st+1)*512 + cb+q] = f2b(nh);
                }
              }
            }
          }
        }
      }
      BAR(cntG, GM, epG);
    }
  }
}

extern "C" void kernel_launch(void* const* d_in, const int* in_sizes, int n_in,
                              void* d_out, int out_size, void* d_ws, size_t ws_size,
                              hipStream_t stream) {
  Params P;
  P.y     = (const float*)d_in[0];
  P.start = (const float*)d_in[1];
  // d_in[2] = target_length (fixed 32)
  P.eqw  = (const float*)d_in[3];  P.eqb  = (const float*)d_in[4];
  P.eow  = (const float*)d_in[5];  P.eob  = (const float*)d_in[6];
  P.ef1w = (const float*)d_in[7];  P.ef1b = (const float*)d_in[8];
  P.ef2w = (const float*)d_in[9];  P.ef2b = (const float*)d_in[10];
  P.eln1g = (const float*)d_in[11]; P.eln1b = (const float*)d_in[12];
  P.eln2g = (const float*)d_in[13]; P.eln2b = (const float*)d_in[14];
  P.elnfg = (const float*)d_in[15]; P.elnfb = (const float*)d_in[16];
  P.dqw  = (const float*)d_in[17]; P.dqb  = (const float*)d_in[18];
  P.dow  = (const float*)d_in[19]; P.dob  = (const float*)d_in[20];
  P.dxqw = (const float*)d_in[21]; P.dxqb = (const float*)d_in[22];
  P.dxow = (const float*)d_in[23]; P.dxob = (const float*)d_in[24];
  P.df1w = (const float*)d_in[25]; P.df1b = (const float*)d_in[26];
  P.df2w = (const float*)d_in[27]; P.df2b = (const float*)d_in[28];
  P.dln1g = (const float*)d_in[29]; P.dln1b = (const float*)d_in[30];
  P.dln2g = (const float*)d_in[31]; P.dln2b = (const float*)d_in[32];
  P.dln3g = (const float*)d_in[33]; P.dln3b = (const float*)d_in[34];
  P.dlnfg = (const float*)d_in[35]; P.dlnfb = (const float*)d_in[36];
  P.out = (float*)d_out;
  P.ws  = (float*)d_ws;
  hipMemsetAsync(d_ws, 0, 4096, stream);   // zero all barrier counters
  hipLaunchKernelGGL(ar_transformer, dim3(NB), dim3(NT), 0, stream, P);
}